// Round 18
// baseline (49.502 us; speedup 1.0000x reference)
//
#include <hip/hip_runtime.h>
#include <hip/hip_fp16.h>

// Joint bilateral filter block — slice-ring LDS staging (stage/conv overlap
// within block), deep-batched prologue, 4-wave j-split.
// x (1,1,20,96,96) f32; guide_im (N,343) f32, N = 16*96*96 = 147456;
// out n = dd*9216 + h*96 + w uses x depths dd+1..dd+3, H/W zero-pad.
//
// History: r17 deep-batched staging 51.4->46.1us — MLP was the limiter all
// along (staging held ~4 loads/wave in flight = 2.1 TB/s ceiling by
// Little's law). r15 ring = right structure, killed by (256,4) VGPR cap 64
// spill (28MB scratch) + shallow slice-serial prologue. This round: ring +
// (256,2) cap 128 (no spill) + r17-style deep prologue (all 3 slices' loads
// in flight before first ds_write). LDS 28.7KB -> 4-5 blocks/CU.

#define NPATCH 147456
#define TPB     256         // 4 waves
#define PPB      64         // patches per block
#define NBLK   (NPATCH / PPB)   // 2304
#define RING_DW 1792        // dwords per slice buffer: 64 patches * 28
#define SLICE_ROWS 448      // 64 patches * 7 rows

typedef float f4u __attribute__((ext_vector_type(4), aligned(4)));
typedef float f2u __attribute__((ext_vector_type(2), aligned(4)));

// ---------------- Kernel A: domain branch (runs once, 1 block) --------------
__global__ __launch_bounds__(128) void domain_branch_kernel(
    const float* __restrict__ dn,
    const float* __restrict__ w1, const float* __restrict__ b1,
    const float* __restrict__ w2, const float* __restrict__ b2,
    float* __restrict__ dom_out)
{
    __shared__ float s_in[344];
    __shared__ float s_c1[128];
    const int t = threadIdx.x;
    for (int idx = t; idx < 343; idx += 128) s_in[idx] = dn[idx];
    __syncthreads();
    if (t < 125) {
        const int i = t / 25, j = (t / 5) % 5, k = t % 5;
        float acc = b1[0];
        const float* base = &s_in[i * 49 + j * 7 + k];
#pragma unroll
        for (int dz = 0; dz < 3; ++dz)
#pragma unroll
            for (int dy = 0; dy < 3; ++dy)
#pragma unroll
                for (int dx = 0; dx < 3; ++dx)
                    acc = fmaf(base[dz * 49 + dy * 7 + dx], w1[dz * 9 + dy * 3 + dx], acc);
        s_c1[t] = fmaxf(acc, 0.f);
    }
    __syncthreads();
    if (t < 27) {
        const int dz = t / 9, dy = (t / 3) % 3, dx = t % 3;
        float acc = b2[0];
#pragma unroll
        for (int u = 0; u < 3; ++u)
#pragma unroll
            for (int v = 0; v < 3; ++v)
#pragma unroll
                for (int q = 0; q < 3; ++q)
                    acc = fmaf(s_c1[(dz + u) * 25 + (dy + v) * 5 + (dx + q)],
                               w2[u * 9 + v * 3 + q], acc);
        dom_out[t] = fmaxf(acc, 0.f);
    }
}

// ---------------- helpers ----------------
__device__ __forceinline__ float h2f_lo(unsigned int q) {
    return __half2float(__ushort_as_half((unsigned short)(q & 0xffffu)));
}
__device__ __forceinline__ float h2f_hi(unsigned int q) {
    return __half2float(__ushort_as_half((unsigned short)(q >> 16)));
}
__device__ __forceinline__ unsigned int pkh(float lo, float hi) {
    return __builtin_bit_cast(unsigned int, __builtin_amdgcn_cvt_pkrtz(lo, hi));
}

struct RowF { f4u a; f2u b; float c; };
__device__ __forceinline__ RowF load7(const float* __restrict__ s) {
    RowF r;
    r.a = *reinterpret_cast<const f4u*>(s);
    r.b = *reinterpret_cast<const f2u*>(s + 4);
    r.c = s[6];
    return r;
}
__device__ __forceinline__ void write7(unsigned int* dst, const RowF& r) {
    uint4 q;
    q.x = pkh(r.a.x, r.a.y); q.y = pkh(r.a.z, r.a.w);
    q.z = pkh(r.b.x, r.b.y); q.w = pkh(r.c, 0.f);
    *reinterpret_cast<uint4*>(dst) = q;
}
__device__ __forceinline__ void unpack7(const uint4 q, float* d) {
    d[0] = h2f_lo(q.x); d[1] = h2f_hi(q.x);
    d[2] = h2f_lo(q.y); d[3] = h2f_hi(q.y);
    d[4] = h2f_lo(q.z); d[5] = h2f_hi(q.z);
    d[6] = h2f_lo(q.w);
}

// c1 row (i, J) + fused conv2 accumulation. s0/s1/s2 = this lane's base in
// the ring buffers holding slices i, i+1, i+2; i folds per unrolled caller.
template<int J>
__device__ __forceinline__ void crow(const unsigned int* __restrict__ s0,
                                     const unsigned int* __restrict__ s1,
                                     const unsigned int* __restrict__ s2,
                                     int i, const float* __restrict__ w1,
                                     float bb1, const float* __restrict__ w2,
                                     float (&a2)[3][3][3])
{
    float rw[3][3][7];
#pragma unroll
    for (int dy = 0; dy < 3; ++dy) {
        unpack7(*reinterpret_cast<const uint4*>(s0 + (J + dy) * 4), rw[0][dy]);
        unpack7(*reinterpret_cast<const uint4*>(s1 + (J + dy) * 4), rw[1][dy]);
        unpack7(*reinterpret_cast<const uint4*>(s2 + (J + dy) * 4), rw[2][dy]);
    }

    float c1r[5];
#pragma unroll
    for (int k = 0; k < 5; ++k) {
        float a = bb1;
#pragma unroll
        for (int u = 0; u < 3; ++u)
#pragma unroll
            for (int v = 0; v < 3; ++v)
#pragma unroll
                for (int w = 0; w < 3; ++w)
                    a = fmaf(rw[u][v][k + w], w1[u * 9 + v * 3 + w], a);
        c1r[k] = fmaxf(a, 0.f);
    }

    constexpr int DY0 = (J - 2 < 0) ? 0 : J - 2;
    constexpr int DY1 = (J < 2) ? J : 2;
#pragma unroll
    for (int dz2 = 0; dz2 < 3; ++dz2) {
        const int u2 = i - dz2;
        if (u2 >= 0 && u2 < 3) {
#pragma unroll
            for (int dy2 = DY0; dy2 <= DY1; ++dy2) {
                const int v2 = J - dy2;
#pragma unroll
                for (int dx2 = 0; dx2 < 3; ++dx2)
#pragma unroll
                    for (int q = 0; q < 3; ++q)
                        a2[dz2][dy2][dx2] = fmaf(c1r[dx2 + q],
                                                 w2[u2 * 9 + v2 * 3 + q],
                                                 a2[dz2][dy2][dx2]);
            }
        }
    }
}

// ---------------- Kernel B: range branch + bilateral combine ----------------
__global__ __launch_bounds__(TPB, 2) void jbf_main_kernel(
    const float* __restrict__ guide, const float* __restrict__ x,
    const float* __restrict__ w1, const float* __restrict__ b1,
    const float* __restrict__ w2, const float* __restrict__ b2,
    const float* __restrict__ dom, float* __restrict__ out)
{
    __shared__ unsigned int ring[4 * RING_DW];   // 28,672 B

    const int tid  = threadIdx.x;
    const int wid  = tid >> 6;      // wave 0..3
    const int lane = tid & 63;      // patch owned by this thread
    const int blk  = blockIdx.x;
    const int n    = blk * PPB + lane;

    // ---- wave 0: issue the 27 scattered x loads early ----
    float xv[27];
    if (wid == 0) {
        const int dd  = n / 9216;
        const int rem = n - dd * 9216;
        const int h   = rem / 96;
        const int w_  = rem - h * 96;
#pragma unroll
        for (int dz = 0; dz < 3; ++dz)
#pragma unroll
            for (int dy = 0; dy < 3; ++dy)
#pragma unroll
                for (int dx = 0; dx < 3; ++dx) {
                    const int yy = h - 1 + dy, xx = w_ - 1 + dx;
                    float v = 0.f;
                    if (yy >= 0 && yy < 96 && xx >= 0 && xx < 96)
                        v = x[(dd + 1 + dz) * 9216 + yy * 96 + xx];
                    xv[dz * 9 + dy * 3 + dx] = v;
                }
    }

    // ---- hoisted staging coordinates (row-per-thread; 448 rows/slice) ----
    const float* __restrict__ srcf = guide + (size_t)blk * (PPB * 343);
    const int p1 = tid / 7,  y1 = tid - p1 * 7;
    const int R2 = tid + TPB;
    const int p2 = R2 / 7,   y2 = R2 - p2 * 7;
    const bool has2 = (R2 < SLICE_ROWS);          // tid < 192 (waves 0..2)
    const float* __restrict__ srow1 = srcf + p1 * 343 + y1 * 7;
    const float* __restrict__ srow2 = srcf + p2 * 343 + y2 * 7;
    unsigned int* const d1 = ring + p1 * 28 + y1 * 4;
    unsigned int* const d2 = ring + p2 * 28 + y2 * 4;

    // ---- DEEP prologue: issue ALL slice-0..2 loads, fence, then write ----
    {
        RowF ra[3], rb[3];
#pragma unroll
        for (int s = 0; s < 3; ++s) {
            ra[s] = load7(srow1 + s * 49);
            if (has2) rb[s] = load7(srow2 + s * 49);
        }
        __builtin_amdgcn_sched_barrier(0);        // keep loads above writes
#pragma unroll
        for (int s = 0; s < 3; ++s) {
            write7(d1 + s * RING_DW, ra[s]);
            if (has2) write7(d2 + s * RING_DW, rb[s]);
        }
    }
    __syncthreads();

    const float bb1 = b1[0];
    float a2[3][3][3];
#pragma unroll
    for (int a = 0; a < 3; ++a)
#pragma unroll
        for (int b = 0; b < 3; ++b)
#pragma unroll
            for (int c = 0; c < 3; ++c) a2[a][b][c] = 0.f;

    // ---- slab loop: stage-issue(slice i+3) / compute(slab i) / write ----
#pragma unroll
    for (int i = 0; i <= 4; ++i) {
        RowF ra, rb;
        if (i < 4) {
            ra = load7(srow1 + (i + 3) * 49);           // issue early (T14)
            if (has2) rb = load7(srow2 + (i + 3) * 49);
        }

        const unsigned int* s0 = ring + ((i + 0) & 3) * RING_DW + lane * 28;
        const unsigned int* s1 = ring + ((i + 1) & 3) * RING_DW + lane * 28;
        const unsigned int* s2 = ring + ((i + 2) & 3) * RING_DW + lane * 28;
        if      (wid == 0) crow<0>(s0, s1, s2, i, w1, bb1, w2, a2);
        else if (wid == 1) crow<1>(s0, s1, s2, i, w1, bb1, w2, a2);
        else if (wid == 2) crow<2>(s0, s1, s2, i, w1, bb1, w2, a2);
        else { crow<3>(s0, s1, s2, i, w1, bb1, w2, a2);
               crow<4>(s0, s1, s2, i, w1, bb1, w2, a2); }

        if (i < 4) {
            write7(d1 + ((i + 3) & 3) * RING_DW, ra);   // write late (T14)
            if (has2) write7(d2 + ((i + 3) & 3) * RING_DW, rb);
        }
        __syncthreads();
    }

    // ---- partials exchange (ring is dead -> alias as f32) ----
    float* part = reinterpret_cast<float*>(ring);       // 3*1728 f32 = 20.7 KB
    if (wid != 0) {
#pragma unroll
        for (int t = 0; t < 27; ++t)
            part[(wid - 1) * 1728 + lane * 27 + t] = a2[t / 9][(t / 3) % 3][t % 3];
    }
    __syncthreads();

    // ---- combine + bilateral (wave 0) ----
    if (wid == 0) {
        const float bb2 = b2[0];
        float num = 0.f, den = 0.f;
#pragma unroll
        for (int t = 0; t < 27; ++t) {
            float r2v = bb2 + a2[t / 9][(t / 3) % 3][t % 3]
                      + part[0 * 1728 + lane * 27 + t]
                      + part[1 * 1728 + lane * 27 + t]
                      + part[2 * 1728 + lane * 27 + t];
            r2v = fmaxf(r2v, 0.f);
            const float wt = fmaf(dom[t], r2v, 1e-10f);
            num = fmaf(wt, xv[t], num);
            den += wt;
        }
        out[n] = num / den;
    }
}

extern "C" void kernel_launch(void* const* d_in, const int* in_sizes, int n_in,
                              void* d_out, int out_size, void* d_ws, size_t ws_size,
                              hipStream_t stream) {
    const float* x     = (const float*)d_in[0];
    const float* dn    = (const float*)d_in[1];
    const float* guide = (const float*)d_in[2];
    const float* w1_d  = (const float*)d_in[3];
    const float* b1_d  = (const float*)d_in[4];
    const float* w2_d  = (const float*)d_in[5];
    const float* b2_d  = (const float*)d_in[6];
    const float* w1_r  = (const float*)d_in[7];
    const float* b1_r  = (const float*)d_in[8];
    const float* w2_r  = (const float*)d_in[9];
    const float* b2_r  = (const float*)d_in[10];
    float* out = (float*)d_out;
    float* dom = (float*)d_ws;   // 27 floats of scratch

    domain_branch_kernel<<<1, 128, 0, stream>>>(dn, w1_d, b1_d, w2_d, b2_d, dom);
    jbf_main_kernel<<<NBLK, TPB, 0, stream>>>(guide, x, w1_r, b1_r, w2_r,
                                              b2_r, dom, out);
}